// Round 1
// baseline (468.089 us; speedup 1.0000x reference)
//
#include <hip/hip_runtime.h>

// Problem constants (B,C,D,H,W,P = 2,8,64,192,192,15; k = 10%)
#define R_      16            // B*C rows
#define NROW    2359296       // D*H*W
#define N4      589824        // NROW/4
#define HW4     9216          // (H*W)/4
#define W4_     48            // W/4
#define KSEL    235930u       // round(NROW * 0.1)
#define NBIN1   2048
#define NBIN2   4096

// ws layout (bytes)
#define OFF_H1C 0             // 16*2048*4 = 131072
#define OFF_H1S 131072        // 131072
#define OFF_H2C 262144        // 16*4096*4 = 262144
#define OFF_H2S 524288        // 262144
#define OFF_META 786432       // Tbin[16] u32, cntAbove[16] u32, sumAbove[16] f64, rowSum[16] f64
#define ZERO_BYTES 786432     // zero both histogram regions

// BCE-with-logits, numerically stable; MUST be bit-identical in both passes.
__device__ __forceinline__ float loss_fn(float xv, float t) {
    float lg = __logf(1.0f + __expf(-fabsf(xv)));
    return __builtin_fmaf(-xv, t, fmaxf(xv, 0.0f)) + lg;
}

// Pass 1: per-row 2048-bin histogram (count+sum) of loss top-12 bits.
__global__ __launch_bounds__(256) void k_hist1(
    const float* __restrict__ x, const float* __restrict__ patch,
    const int* __restrict__ bboxes,
    unsigned* __restrict__ h1_cnt, float* __restrict__ h1_sum)
{
    __shared__ unsigned s_cnt[NBIN1];
    __shared__ float    s_sum[NBIN1];
    const int row = blockIdx.y;
    for (int i = threadIdx.x; i < NBIN1; i += blockDim.x) { s_cnt[i] = 0u; s_sum[i] = 0.0f; }
    __syncthreads();

    const int b  = row >> 3;
    const int z0 = bboxes[row*3+0], y0 = bboxes[row*3+1], x0 = bboxes[row*3+2];
    const float* __restrict__ xr = x + (size_t)row * NROW;
    const float* __restrict__ pb = patch + b * 3375;

    for (int i4 = blockIdx.x * blockDim.x + threadIdx.x; i4 < N4;
         i4 += gridDim.x * blockDim.x) {
        const float4 v = reinterpret_cast<const float4*>(xr)[i4];
        const int d  = i4 / HW4;
        const int r1 = i4 - d * HW4;
        const int h  = r1 / W4_;
        const int w  = (r1 - h * W4_) * 4;
        const float vv[4] = {v.x, v.y, v.z, v.w};
        #pragma unroll
        for (int j = 0; j < 4; ++j) {
            const float xv = vv[j];
            float t = 0.0f;
            const int wj = w + j;
            if ((unsigned)(d - z0) < 15u && (unsigned)(h - y0) < 15u &&
                (unsigned)(wj - x0) < 15u)
                t = pb[(d - z0) * 225 + (h - y0) * 15 + (wj - x0)];
            const float loss = loss_fn(xv, t);
            const unsigned bin = __float_as_uint(loss) >> 20;  // loss >= 0 -> bin < 2048
            atomicAdd(&s_cnt[bin], 1u);
            atomicAdd(&s_sum[bin], loss);
        }
    }
    __syncthreads();
    unsigned* gc = h1_cnt + row * NBIN1;
    float*    gs = h1_sum + row * NBIN1;
    for (int i = threadIdx.x; i < NBIN1; i += blockDim.x) {
        const unsigned c = s_cnt[i];
        if (c) { atomicAdd(&gc[i], c); atomicAdd(&gs[i], s_sum[i]); }
    }
}

// Select level-1 threshold bin per row (1 wave per row).
__global__ __launch_bounds__(64) void k_select1(
    const unsigned* __restrict__ h1_cnt, const float* __restrict__ h1_sum,
    unsigned* __restrict__ Tbin, unsigned* __restrict__ cntAbove,
    double* __restrict__ sumAbove)
{
    const int row = blockIdx.x;
    const int lane = threadIdx.x;
    const unsigned* cnt = h1_cnt + row * NBIN1;
    const float*    sum = h1_sum + row * NBIN1;
    unsigned cum = 0; double cums = 0.0;
    for (int base = NBIN1; base > 0; base -= 64) {
        const int idx = base - 1 - lane;           // lane 0 = highest bin in chunk
        const unsigned c = cnt[idx];
        const float    s = sum[idx];
        unsigned ic = c; float is = s;
        #pragma unroll
        for (int off = 1; off < 64; off <<= 1) {
            const unsigned oc = __shfl_up(ic, off);
            const float    os = __shfl_up(is, off);
            if (lane >= off) { ic += oc; is += os; }
        }
        const unsigned tot  = __shfl(ic, 63);
        const float    tots = __shfl(is, 63);
        if (cum + tot >= KSEL) {
            const unsigned long long mask = __ballot(cum + ic >= KSEL);
            const int tl = __ffsll((unsigned long long)mask) - 1;
            const unsigned ic_tl = __shfl(ic, tl);
            const float    is_tl = __shfl(is, tl);
            const unsigned c_tl  = __shfl(c, tl);
            const float    s_tl  = __shfl(s, tl);
            if (lane == 0) {
                Tbin[row]     = (unsigned)(base - 1 - tl);
                cntAbove[row] = cum + ic_tl - c_tl;                   // strictly above T
                sumAbove[row] = cums + (double)is_tl - (double)s_tl;
            }
            return;
        }
        cum += tot; cums += (double)tots;
    }
    if (lane == 0) { Tbin[row] = 0u; cntAbove[row] = cum; sumAbove[row] = cums; }
}

// Pass 2: level-2 histogram (bits 19..8) of elements in the threshold bin.
__global__ __launch_bounds__(256) void k_hist2(
    const float* __restrict__ x, const float* __restrict__ patch,
    const int* __restrict__ bboxes, const unsigned* __restrict__ Tbin,
    unsigned* __restrict__ h2_cnt, float* __restrict__ h2_sum)
{
    __shared__ unsigned s_cnt[NBIN2];
    __shared__ float    s_sum[NBIN2];
    const int row = blockIdx.y;
    const unsigned T = Tbin[row];
    for (int i = threadIdx.x; i < NBIN2; i += blockDim.x) { s_cnt[i] = 0u; s_sum[i] = 0.0f; }
    __syncthreads();

    const int b  = row >> 3;
    const int z0 = bboxes[row*3+0], y0 = bboxes[row*3+1], x0 = bboxes[row*3+2];
    const float* __restrict__ xr = x + (size_t)row * NROW;
    const float* __restrict__ pb = patch + b * 3375;

    for (int i4 = blockIdx.x * blockDim.x + threadIdx.x; i4 < N4;
         i4 += gridDim.x * blockDim.x) {
        const float4 v = reinterpret_cast<const float4*>(xr)[i4];
        const int d  = i4 / HW4;
        const int r1 = i4 - d * HW4;
        const int h  = r1 / W4_;
        const int w  = (r1 - h * W4_) * 4;
        const float vv[4] = {v.x, v.y, v.z, v.w};
        #pragma unroll
        for (int j = 0; j < 4; ++j) {
            const float xv = vv[j];
            float t = 0.0f;
            const int wj = w + j;
            if ((unsigned)(d - z0) < 15u && (unsigned)(h - y0) < 15u &&
                (unsigned)(wj - x0) < 15u)
                t = pb[(d - z0) * 225 + (h - y0) * 15 + (wj - x0)];
            const float loss = loss_fn(xv, t);
            const unsigned bits = __float_as_uint(loss);
            if ((bits >> 20) == T) {
                const unsigned b2 = (bits >> 8) & (NBIN2 - 1);
                atomicAdd(&s_cnt[b2], 1u);
                atomicAdd(&s_sum[b2], loss);
            }
        }
    }
    __syncthreads();
    unsigned* gc = h2_cnt + row * NBIN2;
    float*    gs = h2_sum + row * NBIN2;
    for (int i = threadIdx.x; i < NBIN2; i += blockDim.x) {
        const unsigned c = s_cnt[i];
        if (c) { atomicAdd(&gc[i], c); atomicAdd(&gs[i], s_sum[i]); }
    }
}

// Select within the threshold bin; emit per-row top-k sum.
__global__ __launch_bounds__(64) void k_select2(
    const unsigned* __restrict__ h2_cnt, const float* __restrict__ h2_sum,
    const unsigned* __restrict__ cntAbove, const double* __restrict__ sumAbove,
    double* __restrict__ rowSum)
{
    const int row = blockIdx.x;
    const int lane = threadIdx.x;
    const unsigned j = KSEL - cntAbove[row];   // >= 1 by construction
    const unsigned* cnt = h2_cnt + row * NBIN2;
    const float*    sum = h2_sum + row * NBIN2;
    unsigned cum = 0; double cums = 0.0;
    for (int base = NBIN2; base > 0; base -= 64) {
        const int idx = base - 1 - lane;
        const unsigned c = cnt[idx];
        const float    s = sum[idx];
        unsigned ic = c; float is = s;
        #pragma unroll
        for (int off = 1; off < 64; off <<= 1) {
            const unsigned oc = __shfl_up(ic, off);
            const float    os = __shfl_up(is, off);
            if (lane >= off) { ic += oc; is += os; }
        }
        const unsigned tot  = __shfl(ic, 63);
        const float    tots = __shfl(is, 63);
        if (cum + tot >= j) {
            const unsigned long long mask = __ballot(cum + ic >= j);
            const int tl = __ffsll((unsigned long long)mask) - 1;
            const unsigned ic_tl = __shfl(ic, tl);
            const float    is_tl = __shfl(is, tl);
            const unsigned c_tl  = __shfl(c, tl);
            const float    s_tl  = __shfl(s, tl);
            if (lane == 0) {
                const unsigned above = cum + ic_tl - c_tl;
                const double aboves = cums + (double)is_tl - (double)s_tl;
                const unsigned rem = j - above;               // in [1, c_tl]
                const double partial = (double)rem * ((double)s_tl / (double)c_tl);
                rowSum[row] = sumAbove[row] + aboves + partial;
            }
            return;
        }
        cum += tot; cums += (double)tots;
    }
    if (lane == 0) rowSum[row] = sumAbove[row] + cums;  // fallback (shouldn't hit)
}

__global__ __launch_bounds__(64) void k_final(const double* __restrict__ rowSum,
                                              float* __restrict__ out)
{
    if (threadIdx.x == 0) {
        double t = 0.0;
        #pragma unroll
        for (int r = 0; r < R_; ++r) t += rowSum[r];
        out[0] = (float)(t / ((double)R_ * (double)KSEL));
    }
}

extern "C" void kernel_launch(void* const* d_in, const int* in_sizes, int n_in,
                              void* d_out, int out_size, void* d_ws, size_t ws_size,
                              hipStream_t stream) {
    const float* x      = (const float*)d_in[0];   // net_output [2,8,64,192,192]
    const float* patch  = (const float*)d_in[1];   // target_structure [2,15,15,15]
    const int*   bboxes = (const int*)d_in[2];     // [2,8,3]
    float* out = (float*)d_out;

    char* ws = (char*)d_ws;
    unsigned* h1_cnt   = (unsigned*)(ws + OFF_H1C);
    float*    h1_sum   = (float*)(ws + OFF_H1S);
    unsigned* h2_cnt   = (unsigned*)(ws + OFF_H2C);
    float*    h2_sum   = (float*)(ws + OFF_H2S);
    unsigned* Tbin     = (unsigned*)(ws + OFF_META);
    unsigned* cntAbove = Tbin + 16;
    double*   sumAbove = (double*)(ws + OFF_META + 256);
    double*   rowSum   = sumAbove + 16;

    hipMemsetAsync(ws, 0, ZERO_BYTES, stream);

    dim3 gridH(128, R_), blockH(256);
    k_hist1<<<gridH, blockH, 0, stream>>>(x, patch, bboxes, h1_cnt, h1_sum);
    k_select1<<<R_, 64, 0, stream>>>(h1_cnt, h1_sum, Tbin, cntAbove, sumAbove);
    k_hist2<<<gridH, blockH, 0, stream>>>(x, patch, bboxes, Tbin, h2_cnt, h2_sum);
    k_select2<<<R_, 64, 0, stream>>>(h2_cnt, h2_sum, cntAbove, sumAbove, rowSum);
    k_final<<<1, 64, 0, stream>>>(rowSum, out);
}

// Round 2
// 331.920 us; speedup vs baseline: 1.4102x; 1.4102x over previous
//
#include <hip/hip_runtime.h>

// Problem constants (B,C,D,H,W,P = 2,8,64,192,192,15; k = 10%)
#define R_      16            // B*C rows
#define NROW    2359296       // D*H*W
#define N4      589824        // NROW/4
#define STRIDE4 32768         // 128 blocks x 256 threads
#define ITERS   9             // N4 / STRIDE4 / 2 (2x unrolled)
#define HW4     9216          // (H*W)/4
#define W4_     48            // W/4
#define KSEL    235930u       // round(NROW * 0.1)
#define NBIN1   2048          // top-11 bits of flipped x key
#define NC1     4             // histogram copies (bank-interleaved)
#define NBIN2   4096          // key bits 20..9

// ws layout (bytes)
#define OFF_H1C  0            // 16*2048*4 = 131072
#define OFF_H2C  131072       // 16*4096*4 = 262144
#define OFF_H2S  393216       // 262144
#define OFF_META 655360       // Tbin[16] u32 | cntAbove[16] u32 | sumAbove[16] f64 | rowSum[16] f64
#define ZERO_BYTES (655360 + 512)

// BCE-with-logits, numerically stable; bit-identical across passes.
__device__ __forceinline__ float loss_fn(float xv, float t) {
    float lg = __logf(1.0f + __expf(-fabsf(xv)));
    return __builtin_fmaf(-xv, t, fmaxf(xv, 0.0f)) + lg;
}

// Order-preserving float->uint key (total order, increasing).
__device__ __forceinline__ unsigned flip_key(float v) {
    unsigned u = __float_as_uint(v);
    return u ^ (unsigned)(((int)u >> 31) | 0x80000000);
}

// Patch element: map loss back to equivalent-x so one key space ranks everything.
__device__ __forceinline__ unsigned patch_key(float L) {
    return flip_key(__logf(expm1f(L)));
}

// Pass 1: per-row count-only histogram of key top-11 bits, 4 interleaved copies.
__global__ __launch_bounds__(256) void k_pass1(
    const float* __restrict__ x, const float* __restrict__ patch,
    const int* __restrict__ bboxes, unsigned* __restrict__ h1_cnt)
{
    __shared__ unsigned s_cnt[NBIN1 * NC1];   // 32 KB
    const int row = blockIdx.y;
    for (int i = threadIdx.x; i < NBIN1 * NC1; i += 256) s_cnt[i] = 0u;
    __syncthreads();

    const int b  = row >> 3;
    const int z0 = bboxes[row*3+0], y0 = bboxes[row*3+1], x0 = bboxes[row*3+2];
    const float* __restrict__ pb = patch + b * 3375;
    const float4* __restrict__ X4 =
        reinterpret_cast<const float4*>(x + (size_t)row * NROW);
    const int c = threadIdx.x & (NC1 - 1);

    int i4 = blockIdx.x * 256 + threadIdx.x;
    for (int it = 0; it < ITERS; ++it, i4 += 2 * STRIDE4) {
        const float4 va = X4[i4];
        const float4 vb = X4[i4 + STRIDE4];
        #pragma unroll
        for (int half = 0; half < 2; ++half) {
            const int ii = half ? (i4 + STRIDE4) : i4;
            const float4 v = half ? vb : va;
            const int d  = ii / HW4;
            const int r1 = ii - d * HW4;
            const int h  = r1 / W4_;
            const int w  = (r1 - h * W4_) * 4;
            const float vv[4] = {v.x, v.y, v.z, v.w};
            const bool dh_in = ((unsigned)(d - z0) < 15u) && ((unsigned)(h - y0) < 15u);
            #pragma unroll
            for (int j = 0; j < 4; ++j) {
                unsigned key;
                const int wj = w + j;
                if (dh_in && (unsigned)(wj - x0) < 15u) {
                    const float L = loss_fn(vv[j], pb[(d-z0)*225 + (h-y0)*15 + (wj-x0)]);
                    key = patch_key(L);
                } else {
                    key = flip_key(vv[j]);
                }
                atomicAdd(&s_cnt[(key >> 21) * NC1 + c], 1u);
            }
        }
    }
    __syncthreads();
    unsigned* gc = h1_cnt + row * NBIN1;
    for (int i = threadIdx.x; i < NBIN1; i += 256) {
        const unsigned t = s_cnt[i*NC1] + s_cnt[i*NC1+1] + s_cnt[i*NC1+2] + s_cnt[i*NC1+3];
        if (t) atomicAdd(&gc[i], t);
    }
}

// Select level-1 threshold bin per row (1 wave per row). Count-only.
__global__ __launch_bounds__(64) void k_select1(
    const unsigned* __restrict__ h1_cnt,
    unsigned* __restrict__ Tbin, unsigned* __restrict__ cntAbove)
{
    const int row = blockIdx.x;
    const int lane = threadIdx.x;
    const unsigned* cnt = h1_cnt + row * NBIN1;
    unsigned cum = 0;
    for (int base = NBIN1; base > 0; base -= 64) {
        const int idx = base - 1 - lane;           // lane 0 = highest bin in chunk
        const unsigned cv = cnt[idx];
        unsigned ic = cv;
        #pragma unroll
        for (int off = 1; off < 64; off <<= 1) {
            const unsigned oc = __shfl_up(ic, off);
            if (lane >= off) ic += oc;
        }
        const unsigned tot = __shfl(ic, 63);
        if (cum + tot >= KSEL) {
            const unsigned long long mask = __ballot(cum + ic >= KSEL);
            const int tl = __ffsll((unsigned long long)mask) - 1;
            const unsigned ic_tl = __shfl(ic, tl);
            const unsigned c_tl  = __shfl(cv, tl);
            if (lane == 0) {
                Tbin[row]     = (unsigned)(base - 1 - tl);
                cntAbove[row] = cum + ic_tl - c_tl;    // strictly above T
            }
            return;
        }
        cum += tot;
    }
    if (lane == 0) { Tbin[row] = 0u; cntAbove[row] = cum; }
}

// Pass 2: register-accumulate losses strictly above tie bin; level-2 hist for tie bin.
__global__ __launch_bounds__(256) void k_pass2(
    const float* __restrict__ x, const float* __restrict__ patch,
    const int* __restrict__ bboxes, const unsigned* __restrict__ Tbin,
    unsigned* __restrict__ h2_cnt, float* __restrict__ h2_sum,
    double* __restrict__ sumAbove)
{
    __shared__ unsigned s2c[NBIN2];   // 16 KB
    __shared__ float    s2s[NBIN2];   // 16 KB
    __shared__ double   s_red[4];
    const int row = blockIdx.y;
    const unsigned T = Tbin[row];
    for (int i = threadIdx.x; i < NBIN2; i += 256) { s2c[i] = 0u; s2s[i] = 0.0f; }
    __syncthreads();

    const int b  = row >> 3;
    const int z0 = bboxes[row*3+0], y0 = bboxes[row*3+1], x0 = bboxes[row*3+2];
    const float* __restrict__ pb = patch + b * 3375;
    const float4* __restrict__ X4 =
        reinterpret_cast<const float4*>(x + (size_t)row * NROW);

    float acc = 0.0f;
    int i4 = blockIdx.x * 256 + threadIdx.x;
    for (int it = 0; it < ITERS; ++it, i4 += 2 * STRIDE4) {
        const float4 va = X4[i4];
        const float4 vb = X4[i4 + STRIDE4];
        #pragma unroll
        for (int half = 0; half < 2; ++half) {
            const int ii = half ? (i4 + STRIDE4) : i4;
            const float4 v = half ? vb : va;
            const int d  = ii / HW4;
            const int r1 = ii - d * HW4;
            const int h  = r1 / W4_;
            const int w  = (r1 - h * W4_) * 4;
            const float vv[4] = {v.x, v.y, v.z, v.w};
            const bool dh_in = ((unsigned)(d - z0) < 15u) && ((unsigned)(h - y0) < 15u);
            #pragma unroll
            for (int j = 0; j < 4; ++j) {
                unsigned key;
                float Lp = 0.0f;
                bool inpatch = false;
                const int wj = w + j;
                if (dh_in && (unsigned)(wj - x0) < 15u) {
                    inpatch = true;
                    Lp = loss_fn(vv[j], pb[(d-z0)*225 + (h-y0)*15 + (wj-x0)]);
                    key = patch_key(Lp);
                } else {
                    key = flip_key(vv[j]);
                }
                const unsigned b1 = key >> 21;
                if (b1 >= T) {
                    const float loss = inpatch ? Lp : loss_fn(vv[j], 0.0f);
                    if (b1 > T) {
                        acc += loss;
                    } else {
                        const unsigned b2 = (key >> 9) & (NBIN2 - 1);
                        atomicAdd(&s2c[b2], 1u);
                        atomicAdd(&s2s[b2], loss);
                    }
                }
            }
        }
    }
    // block-reduce acc -> one double atomic per block
    float a = acc;
    #pragma unroll
    for (int off = 32; off > 0; off >>= 1) a += __shfl_down(a, off);
    __syncthreads();           // also covers s2c/s2s completion
    if ((threadIdx.x & 63) == 0) s_red[threadIdx.x >> 6] = (double)a;
    __syncthreads();
    if (threadIdx.x == 0)
        atomicAdd(&sumAbove[row], s_red[0] + s_red[1] + s_red[2] + s_red[3]);

    unsigned* gc = h2_cnt + row * NBIN2;
    float*    gs = h2_sum + row * NBIN2;
    for (int i = threadIdx.x; i < NBIN2; i += 256) {
        const unsigned cv = s2c[i];
        if (cv) { atomicAdd(&gc[i], cv); atomicAdd(&gs[i], s2s[i]); }
    }
}

// Select within the tie bin; emit per-row top-k sum.
__global__ __launch_bounds__(64) void k_select2(
    const unsigned* __restrict__ h2_cnt, const float* __restrict__ h2_sum,
    const unsigned* __restrict__ cntAbove, const double* __restrict__ sumAbove,
    double* __restrict__ rowSum)
{
    const int row = blockIdx.x;
    const int lane = threadIdx.x;
    const unsigned j = KSEL - cntAbove[row];   // >= 1 by construction
    const unsigned* cnt = h2_cnt + row * NBIN2;
    const float*    sum = h2_sum + row * NBIN2;
    unsigned cum = 0; double cums = 0.0;
    for (int base = NBIN2; base > 0; base -= 64) {
        const int idx = base - 1 - lane;
        const unsigned cv = cnt[idx];
        const float    sv = sum[idx];
        unsigned ic = cv; float is = sv;
        #pragma unroll
        for (int off = 1; off < 64; off <<= 1) {
            const unsigned oc = __shfl_up(ic, off);
            const float    os = __shfl_up(is, off);
            if (lane >= off) { ic += oc; is += os; }
        }
        const unsigned tot  = __shfl(ic, 63);
        const float    tots = __shfl(is, 63);
        if (cum + tot >= j) {
            const unsigned long long mask = __ballot(cum + ic >= j);
            const int tl = __ffsll((unsigned long long)mask) - 1;
            const unsigned ic_tl = __shfl(ic, tl);
            const float    is_tl = __shfl(is, tl);
            const unsigned c_tl  = __shfl(cv, tl);
            const float    s_tl  = __shfl(sv, tl);
            if (lane == 0) {
                const unsigned above = cum + ic_tl - c_tl;
                const double aboves = cums + (double)is_tl - (double)s_tl;
                const unsigned rem = j - above;               // in [1, c_tl]
                const double partial = (double)rem * ((double)s_tl / (double)c_tl);
                rowSum[row] = sumAbove[row] + aboves + partial;
            }
            return;
        }
        cum += tot; cums += (double)tots;
    }
    if (lane == 0) rowSum[row] = sumAbove[row] + cums;  // fallback (shouldn't hit)
}

__global__ __launch_bounds__(64) void k_final(const double* __restrict__ rowSum,
                                              float* __restrict__ out)
{
    if (threadIdx.x == 0) {
        double t = 0.0;
        #pragma unroll
        for (int r = 0; r < R_; ++r) t += rowSum[r];
        out[0] = (float)(t / ((double)R_ * (double)KSEL));
    }
}

extern "C" void kernel_launch(void* const* d_in, const int* in_sizes, int n_in,
                              void* d_out, int out_size, void* d_ws, size_t ws_size,
                              hipStream_t stream) {
    const float* x      = (const float*)d_in[0];   // net_output [2,8,64,192,192]
    const float* patch  = (const float*)d_in[1];   // target_structure [2,15,15,15]
    const int*   bboxes = (const int*)d_in[2];     // [2,8,3]
    float* out = (float*)d_out;

    char* ws = (char*)d_ws;
    unsigned* h1_cnt   = (unsigned*)(ws + OFF_H1C);
    unsigned* h2_cnt   = (unsigned*)(ws + OFF_H2C);
    float*    h2_sum   = (float*)(ws + OFF_H2S);
    unsigned* Tbin     = (unsigned*)(ws + OFF_META);
    unsigned* cntAbove = Tbin + 16;
    double*   sumAbove = (double*)(ws + OFF_META + 128);
    double*   rowSum   = (double*)(ws + OFF_META + 256);

    hipMemsetAsync(ws, 0, ZERO_BYTES, stream);

    dim3 gridH(128, R_), blockH(256);
    k_pass1<<<gridH, blockH, 0, stream>>>(x, patch, bboxes, h1_cnt);
    k_select1<<<R_, 64, 0, stream>>>(h1_cnt, Tbin, cntAbove);
    k_pass2<<<gridH, blockH, 0, stream>>>(x, patch, bboxes, Tbin, h2_cnt, h2_sum, sumAbove);
    k_select2<<<R_, 64, 0, stream>>>(h2_cnt, h2_sum, cntAbove, sumAbove, rowSum);
    k_final<<<1, 64, 0, stream>>>(rowSum, out);
}